// Round 1
// baseline (6989.832 us; speedup 1.0000x reference)
//
#include <hip/hip_runtime.h>
#include <hip/hip_fp16.h>

#define R       8192
#define C1      8213
#define C2      8192
#define CP      8216      // padded row stride (halves / floats), multiple of 8
#define NSPLIT  64        // row splits for column-sum pass
#define RSPLIT  128       // R / NSPLIT

struct __align__(8) h4 { __half2 a, b; };

__device__ __forceinline__ float gm_label(float sc, int lab) {
    if (lab == 0) return fmaxf(-0.02f - sc, 0.0f) + fmaxf(sc, 0.0f);
    if (lab == 3) return fmaxf(0.09f + sc, 0.0f);
    return fmaxf(0.05f + sc, 0.0f) + fmaxf(-0.09f - sc, 0.0f); // labels 1|2
}

__device__ __forceinline__ float kval(float gm) {
    // K = exp(-M/REG) with M = exp(-GM), REG = -0.2  ->  exp(5*exp(-GM))
    return expf(5.0f * expf(-gm));
}

__global__ __launch_bounds__(256) void build_k1(const float* __restrict__ dist,
                                                const int* __restrict__ lab,
                                                __half* __restrict__ K) {
    int row = blockIdx.y;
    int j0 = (blockIdx.x * 256 + threadIdx.x) * 4;
    if (j0 >= C1) return;
    size_t ib = (size_t)row * C1;
    size_t ob = (size_t)row * CP;
    float d0 = dist[ib];
#pragma unroll
    for (int k = 0; k < 4; ++k) {
        int j = j0 + k;
        if (j < C1) {
            float g = gm_label(dist[ib + j] - d0, lab[ib + j]);
            K[ob + j] = __float2half(kval(g));
        }
    }
}

__global__ __launch_bounds__(256) void diag_k(const float* __restrict__ dist,
                                              float* __restrict__ dcol) {
    int j = blockIdx.x * 256 + threadIdx.x;
    if (j < R) dcol[j] = dist[(size_t)j * C1 + 21 + j];
}

__global__ __launch_bounds__(256) void build_k2(const float* __restrict__ dist,
                                                const float* __restrict__ dcol,
                                                __half* __restrict__ K) {
    int row = blockIdx.y;
    int j0 = (blockIdx.x * 256 + threadIdx.x) * 4;
    size_t ib = (size_t)row * C1 + 21;
    size_t ob = (size_t)row * CP;
#pragma unroll
    for (int k = 0; k < 4; ++k) {
        int j = j0 + k;   // C2 = 8192 divisible by grid coverage, no guard needed
        float s = dist[ib + j] - dcol[j];
        float g = (j == row) ? 0.0f : fmaxf(0.09f + s, 0.0f);
        K[ob + j] = __float2half(kval(g));
    }
}

__global__ __launch_bounds__(256) void fill_f(float* __restrict__ p, int n, float val) {
    int i = blockIdx.x * 256 + threadIdx.x;
    if (i < n) p[i] = val;
}

// v-pass part 1: partial column sums  part[s][j] = sum_{r in split s} K[r][j]*u[r]
__global__ __launch_bounds__(256) void col_partial(const __half* __restrict__ K,
                                                   const float* __restrict__ u,
                                                   float* __restrict__ part, int C) {
    __shared__ float us[RSPLIT];
    int sp = blockIdx.y;
    int r0 = sp * RSPLIT;
    if (threadIdx.x < RSPLIT) us[threadIdx.x] = u[r0 + threadIdx.x];
    __syncthreads();
    int j0 = (blockIdx.x * 256 + threadIdx.x) * 4;
    if (j0 >= C) return;
    if (j0 + 3 < C) {
        float a0 = 0, a1 = 0, a2 = 0, a3 = 0;
        const h4* Kp = reinterpret_cast<const h4*>(K + (size_t)r0 * CP + j0);
        for (int r = 0; r < RSPLIT; ++r) {
            h4 kv = Kp[(size_t)r * (CP / 4)];
            float2 f0 = __half22float2(kv.a);
            float2 f1 = __half22float2(kv.b);
            float uu = us[r];
            a0 = fmaf(f0.x, uu, a0);
            a1 = fmaf(f0.y, uu, a1);
            a2 = fmaf(f1.x, uu, a2);
            a3 = fmaf(f1.y, uu, a3);
        }
        *reinterpret_cast<float4*>(part + (size_t)sp * CP + j0) = make_float4(a0, a1, a2, a3);
    } else {
        float acc[4] = {0, 0, 0, 0};
        for (int r = 0; r < RSPLIT; ++r) {
            float uu = us[r];
            const __half* Kr = K + (size_t)(r0 + r) * CP;
#pragma unroll
            for (int k = 0; k < 4; ++k) {
                int j = j0 + k;
                if (j < C) acc[k] = fmaf(__half2float(Kr[j]), uu, acc[k]);
            }
        }
#pragma unroll
        for (int k = 0; k < 4; ++k)
            if (j0 + k < C) part[(size_t)sp * CP + j0 + k] = acc[k];
    }
}

// v-pass part 2: v[j] = bval / sum_s part[s][j]
__global__ __launch_bounds__(256) void col_reduce(const float* __restrict__ part,
                                                  float* __restrict__ v, int C, float bval) {
    int j = blockIdx.x * 256 + threadIdx.x;
    if (j >= C) return;
    float s = 0;
#pragma unroll 8
    for (int k = 0; k < NSPLIT; ++k) s += part[(size_t)k * CP + j];
    v[j] = bval / s;
}

__device__ __forceinline__ float block_reduce_1(float x, float* sbuf) {
#pragma unroll
    for (int off = 32; off; off >>= 1) x += __shfl_down(x, off, 64);
    if ((threadIdx.x & 63) == 0) sbuf[threadIdx.x >> 6] = x;
    __syncthreads();
    float r = sbuf[0] + sbuf[1] + sbuf[2] + sbuf[3];
    __syncthreads();  // safe reuse of sbuf
    return r;
}

__device__ __forceinline__ float2 block_reduce_2(float x, float y, float* sb) {
#pragma unroll
    for (int off = 32; off; off >>= 1) {
        x += __shfl_down(x, off, 64);
        y += __shfl_down(y, off, 64);
    }
    if ((threadIdx.x & 63) == 0) {
        int w = threadIdx.x >> 6;
        sb[w] = x; sb[4 + w] = y;
    }
    __syncthreads();
    float2 r;
    r.x = sb[0] + sb[1] + sb[2] + sb[3];
    r.y = sb[4] + sb[5] + sb[6] + sb[7];
    __syncthreads();
    return r;
}

// u-pass: u[i] = aval / sum_j K[i][j]*v[j]; 8 rows per block, v cached in registers
__global__ __launch_bounds__(256) void row_pass(const __half* __restrict__ K,
                                                const float* __restrict__ v,
                                                float* __restrict__ u, int C, float aval) {
    __shared__ float sbuf[4];
    int tx = threadIdx.x;
    float4 vv[8];
    const float4* v4 = reinterpret_cast<const float4*>(v);
#pragma unroll
    for (int i = 0; i < 8; ++i) vv[i] = v4[tx + i * 256];
    float vt = 0.0f;
    int jt = 8192 + tx;
    if (jt < C) vt = v[jt];
    int r0 = blockIdx.x * 8;
    for (int rr = 0; rr < 8; ++rr) {
        int row = r0 + rr;
        const __half* Kr = K + (size_t)row * CP;
        const h4* K4 = reinterpret_cast<const h4*>(Kr);
        float acc = 0.0f;
#pragma unroll
        for (int i = 0; i < 8; ++i) {
            h4 kv = K4[tx + i * 256];
            float2 f0 = __half22float2(kv.a);
            float2 f1 = __half22float2(kv.b);
            float4 w = vv[i];
            acc = fmaf(f0.x, w.x, acc);
            acc = fmaf(f0.y, w.y, acc);
            acc = fmaf(f1.x, w.z, acc);
            acc = fmaf(f1.y, w.w, acc);
        }
        if (jt < C) acc = fmaf(__half2float(Kr[jt]), vt, acc);
        float tot = block_reduce_1(acc, sbuf);
        if (tx == 0) u[row] = aval / tot;
    }
}

// loss1 per row: ratio[i] = (sum_j GM*K*v) / (sum_j K*v)
__global__ __launch_bounds__(256) void loss1_k(const __half* __restrict__ K,
                                               const float* __restrict__ v,
                                               const float* __restrict__ dist,
                                               const int* __restrict__ lab,
                                               float* __restrict__ ratio) {
    __shared__ float sb[8];
    int i = blockIdx.x;
    size_t ib = (size_t)i * C1;
    float d0 = dist[ib];
    const __half* Kr = K + (size_t)i * CP;
    float num = 0, den = 0;
    for (int j = threadIdx.x; j < C1; j += 256) {
        float kv = __half2float(Kr[j]) * v[j];
        float g = gm_label(dist[ib + j] - d0, lab[ib + j]);
        den += kv;
        num = fmaf(g, kv, num);
    }
    float2 r = block_reduce_2(num, den, sb);
    if (threadIdx.x == 0) ratio[i] = r.x / r.y;
}

// loss2 per row: off-diagonal only; hinge = relu(0.09 + dist[i][21+j] - dcol[j])
__global__ __launch_bounds__(256) void loss2_k(const __half* __restrict__ K,
                                               const float* __restrict__ v,
                                               const float* __restrict__ dist,
                                               const float* __restrict__ dcol,
                                               float* __restrict__ ratio) {
    __shared__ float sb[8];
    int i = blockIdx.x;
    const __half* Kr = K + (size_t)i * CP;
    const float* Dr = dist + (size_t)i * C1 + 21;
    float num = 0, den = 0;
    for (int j = threadIdx.x; j < C2; j += 256) {
        if (j == i) continue;
        float kv = __half2float(Kr[j]) * v[j];
        float h = fmaxf(0.09f + Dr[j] - dcol[j], 0.0f);
        den += kv;
        num = fmaf(h, kv, num);
    }
    float2 r = block_reduce_2(num, den, sb);
    if (threadIdx.x == 0) ratio[i] = r.x / r.y;
}

__global__ __launch_bounds__(256) void final_k(const float* __restrict__ r1,
                                               const float* __restrict__ r2,
                                               float* __restrict__ out) {
    __shared__ float sb[8];
    float s1 = 0, s2 = 0;
    for (int i = threadIdx.x; i < R; i += 256) { s1 += r1[i]; s2 += r2[i]; }
    float2 t = block_reduce_2(s1, s2, sb);
    if (threadIdx.x == 0)
        out[0] = t.x / ((float)R * (float)C1) + t.y / ((float)R * (float)C2);
}

static void run_phase(const __half* K, float* u, float* v, float* part, int C,
                      hipStream_t stream) {
    float aval = 1.0f / (float)R;
    float bval = 1.0f / (float)C;
    fill_f<<<dim3((R + 255) / 256), 256, 0, stream>>>(u, R, aval);
    int gx = (C + 1023) / 1024;
    int gr = (C + 255) / 256;
    for (int t = 0; t < 50; ++t) {
        col_partial<<<dim3(gx, NSPLIT), 256, 0, stream>>>(K, u, part, C);
        col_reduce<<<dim3(gr), 256, 0, stream>>>(part, v, C, bval);
        if (t < 49)
            row_pass<<<dim3(R / 8), 256, 0, stream>>>(K, v, u, C, aval);
    }
}

extern "C" void kernel_launch(void* const* d_in, const int* in_sizes, int n_in,
                              void* d_out, int out_size, void* d_ws, size_t ws_size,
                              hipStream_t stream) {
    const float* dist = (const float*)d_in[0];
    const int* lab = (const int*)d_in[1];
    float* out = (float*)d_out;
    char* ws = (char*)d_ws;

    size_t off = 0;
    __half* K = (__half*)(ws + off);   off += (size_t)R * CP * sizeof(__half);   // 134,610,944
    float* part = (float*)(ws + off);  off += (size_t)NSPLIT * CP * sizeof(float); // 2,103,296
    float* u = (float*)(ws + off);     off += (size_t)R * sizeof(float);
    float* v = (float*)(ws + off);     off += (size_t)CP * sizeof(float);
    float* dcol = (float*)(ws + off);  off += (size_t)R * sizeof(float);
    float* rat1 = (float*)(ws + off);  off += (size_t)R * sizeof(float);
    float* rat2 = (float*)(ws + off);  off += (size_t)R * sizeof(float);
    if (ws_size < off) return;  // workspace too small: bail (will fail validation visibly)

    // ---- phase 1 ----
    build_k1<<<dim3((C1 + 1023) / 1024, R), 256, 0, stream>>>(dist, lab, K);
    run_phase(K, u, v, part, C1, stream);
    loss1_k<<<dim3(R), 256, 0, stream>>>(K, v, dist, lab, rat1);

    // ---- phase 2 (reuses K buffer) ----
    diag_k<<<dim3((R + 255) / 256), 256, 0, stream>>>(dist, dcol);
    build_k2<<<dim3(C2 / 1024, R), 256, 0, stream>>>(dist, dcol, K);
    run_phase(K, u, v, part, C2, stream);
    loss2_k<<<dim3(R), 256, 0, stream>>>(K, v, dist, dcol, rat2);

    final_k<<<dim3(1), 256, 0, stream>>>(rat1, rat2, out);
}